// Round 6
// baseline (85.519 us; speedup 1.0000x reference)
//
#include <hip/hip_runtime.h>

#define NB 8
#define NS 1024
#define NH 8
#define NMONO 56    // monomials (a,b,c), a+b+c <= 5, graded order
#define NTREE 35    // non-leaf monomials (deg <= 4); 35..55 are leaves (deg 5)

// ---------------------------------------------------------------------------
// R18: single fused kernel, channel-split + LIVE-SET TRIM (unroll1, leaf-FMA).
// Quantum layer collapsed analytically (verified R3-R11): c_j = cos(x_j+th_j),
//   q = (prod c1..c7, c0c1, c0c1c2)/8, k = (c0..c3, c0..c4, c0..c5),
//   v = (c0..c6, c0..c7).  Linear attention via deg-5 Taylor of e^{q.k}
//   (|q.k|<=0.375, rel err 8e-6): moments M_ch[i] = sum_t mono_i(k) * w_t,
//   w in {1, v0, v1}; att = phi(q).M_v / phi(q).M_1.
// Ladder so far (total / inferred kernel):
//   R13 512thr shared-tree: 100.5 / 44  (spill: WRITE 47MB vs 2.4MB output)
//   R14 launch_bounds(512,1): same      (VGPR cap stays 128)
//   R15 LDS-pad + waves_per_eu(2,2): same
//   R16 256thr + pad + waves_per_eu(1): 86.8 / ~35 (still 128-cap spill)
//   R17 768thr channel-split, unroll2:  84.9 / ~33 (unroll2 re-inflated the
//       live set: 56 acc + 2x36 mono + temps ~ 170 > 128 -> partial spill)
// R18: (a) unroll 1 -> one tree live (~119 regs < 128); (b) deg-5 layer
//   (21 leaves, never a PRED) accumulated via single FMA without
//   materializing mono[i] -> mono[NTREE] only, -21 inst/row, -21 regs.
//   inst/row ~125; per-SIMD 3 waves x 32 rows x 125 x 2cyc ~ 24k cyc ~ 10us.
// Grid: 256 blocks = (b = bid>>5, 32-s chunk = bid&31), 1 block/CU,
//   768 thr = 3 channel-groups x 256 (chg = tid>>8: {1, v0, v1}).
//   Phase A: 32 rows/thread; butterfly shfl_xor (8/16/32) over same-h lanes;
//   4 waves/channel combined in LDS with COEF fold.  Phase B: 256 thr eval
//   32 s x 8 h via 56-dim dot from MhL.  Phase C: (32,16)@W^T + bias.
// Known-fixed costs outside our control: ~40.5us 256MiB ws-poison fill in
//   the timed window + ~11us node/launch gaps.
// ---------------------------------------------------------------------------

// graded enumeration; mono[i] = mono[PRED[i]] * k[VARI[i]] (PRED folds at CT)
constexpr int PRED[NMONO] = {
    0,
    0, 0, 0,
    1, 2, 3, 2, 3, 3,
    4, 5, 6, 7, 8, 9, 7, 8, 9, 9,
    10,11,12,13,14,15,16,17,18,19,16,17,18,19,19,
    20,21,22,23,24,25,26,27,28,29,30,31,32,33,34,30,31,32,33,34,34};
constexpr int VARI[NMONO] = {
    0,
    0, 1, 2,
    0, 0, 0, 1, 1, 2,
    0, 0, 0, 0, 0, 0, 1, 1, 1, 2,
    0, 0, 0, 0, 0, 0, 0, 0, 0, 0, 1, 1, 1, 1, 2,
    0, 0, 0, 0, 0, 0, 0, 0, 0, 0, 0, 0, 0, 0, 0, 1, 1, 1, 1, 1, 2};
#define F6 0.166666666666667f
#define F12 0.0833333333333333f
#define F24 0.0416666666666667f
#define F120 0.00833333333333333f
constexpr float COEF[NMONO] = {          // 1/(a! b! c!)
    1.f,
    1.f, 1.f, 1.f,
    0.5f, 1.f, 1.f, 0.5f, 1.f, 0.5f,
    F6, 0.5f, 0.5f, 0.5f, 1.f, 0.5f, F6, 0.5f, 0.5f, F6,
    F24, F6, F6, 0.25f, 0.5f, 0.25f, F6, 0.5f, 0.5f, F6, F24, F6, 0.25f, F6, F24,
    F120, F24, F24, F12, F6, F12, F12, 0.25f, 0.25f, F12, F24, F6, 0.25f, F6, F24,
    F120, F24, F12, F12, F24, F120};

__global__ __launch_bounds__(768) void fused_qattn_kernel(
        const float* __restrict__ x, const float* __restrict__ theta,
        const float* __restrict__ W, const float* __restrict__ bias,
        float* __restrict__ out) {
    __shared__ __align__(16) float redL[12][8][64];   // [wave][h][mono], 24.6 KB
    __shared__ __align__(16) float MhL[8 * 172];      // [h][ch*56+i], padded
    __shared__ float WtL[16 * 65];
    __shared__ float biasL[64];
    __shared__ float attL[32][17];

    const int tid = threadIdx.x;
    const int b = blockIdx.x >> 5;
    const int chunk = blockIdx.x & 31;
    const int s0 = chunk * 32;

    float th[8];
#pragma unroll
    for (int j = 0; j < 8; ++j) th[j] = theta[j];

    // stage projection weights (consumed after barriers in phase C)
    for (int i = tid; i < 1024; i += 768) WtL[(i & 15) * 65 + (i >> 4)] = W[i];
    if (tid < 64) biasL[tid] = bias[tid];

    // ---- phase A: moments; thread = (chg = tid>>8, h = tid&7, tslot) ----
    const int chg = tid >> 8;                         // 0: sum, 1: v0, 2: v1
    const int tg  = tid & 255;
    const int h = tg & 7;
    const int tslot = tg >> 3;                        // 0..31

    float acc[NMONO];
#pragma unroll
    for (int i = 0; i < NMONO; ++i) acc[i] = 0.f;

#pragma unroll 1
    for (int it = 0; it < 32; ++it) {
        const int t = tslot + 32 * it;
        const float4* xp = (const float4*)(x + ((size_t)(b * NS + t)) * 64 + h * 8);
        float4 lo = xp[0], hi = xp[1];
        float c0 = __cosf(lo.x + th[0]);
        float c1 = __cosf(lo.y + th[1]);
        float c2 = __cosf(lo.z + th[2]);
        float c3 = __cosf(lo.w + th[3]);
        float c4 = __cosf(hi.x + th[4]);
        float c5 = __cosf(hi.y + th[5]);
        float c6 = __cosf(hi.z + th[6]);
        float c7 = __cosf(hi.w + th[7]);
        float k0 = ((c0 * c1) * c2) * c3;
        float k1 = k0 * c4;
        float k2 = k1 * c5;
        float v0 = k2 * c6;
        float v1 = v0 * c7;
        float wch = (chg == 0) ? 1.f : ((chg == 1) ? v0 : v1);

        // weight folds into the tree: mono[i] here is true mono * wch.
        // Non-leaf (i < NTREE): materialize + add.  Leaf (i >= NTREE,
        // PRED in deg-4 layer): single FMA into acc, no mono[i] register.
        float mono[NTREE];
        mono[0] = wch;
        acc[0] += wch;
#pragma unroll
        for (int i = 1; i < NMONO; ++i) {
            float var = (VARI[i] == 0) ? k0 : ((VARI[i] == 1) ? k1 : k2);
            if (i < NTREE) {
                mono[i] = mono[PRED[i]] * var;        // PRED[i] folds to literal
                acc[i] += mono[i];
            } else {
                acc[i] = fmaf(mono[PRED[i]], var, acc[i]);
            }
        }
    }

    // butterfly reduce over same-h lanes (spaced 8 apart: lane bits 3,4,5)
#pragma unroll
    for (int i = 0; i < NMONO; ++i) {
        float a = acc[i];
        a += __shfl_xor(a, 8); a += __shfl_xor(a, 16); a += __shfl_xor(a, 32);
        acc[i] = a;
    }

    const int wv = tid >> 6;                          // wave 0..11 = chg*4+wg
    const int l  = tid & 63;
    if (l < 8) {                                      // l == h here
        float* dst = &redL[wv][l][0];
#pragma unroll
        for (int g = 0; g < 14; ++g)
            ((float4*)dst)[g] = make_float4(acc[4*g], acc[4*g+1], acc[4*g+2], acc[4*g+3]);
    }
    __syncthreads();

    // combine the 4 waves of each channel group, fold COEF
    for (int e = tid; e < 8 * 168; e += 768) {
        const int hh = e / 168, j = e - hh * 168;
        const int c = j / 56, i = j - c * 56;
        float s = ((redL[c * 4 + 0][hh][i] + redL[c * 4 + 1][hh][i])
                 + (redL[c * 4 + 2][hh][i] + redL[c * 4 + 3][hh][i]));
        MhL[hh * 172 + j] = s * COEF[i];
    }
    __syncthreads();

    // ---- phase B: eval 32 s x 8 h rows via 56-dim linear attention ----
    if (tid < 256) {
        const int eh = tid >> 5, sl = tid & 31;
        const int s = s0 + sl;
        const float4* xp = (const float4*)(x + ((size_t)(b * NS + s)) * 64 + eh * 8);
        float4 lo = xp[0], hi = xp[1];
        float c0 = __cosf(lo.x + th[0]);
        float c1 = __cosf(lo.y + th[1]);
        float c2 = __cosf(lo.z + th[2]);
        float c3 = __cosf(lo.w + th[3]);
        float c4 = __cosf(hi.x + th[4]);
        float c5 = __cosf(hi.y + th[5]);
        float c6 = __cosf(hi.z + th[6]);
        float c7 = __cosf(hi.w + th[7]);
        float m1 = c0 * c1;
        float m2 = m1 * c2;
        float m0 = ((c1 * c2) * (c3 * c4)) * ((c5 * c6) * c7);
        float q0 = m0 * 0.125f, q1 = m1 * 0.125f, q2 = m2 * 0.125f;

        float mono[NMONO];
        mono[0] = 1.f;
#pragma unroll
        for (int i = 1; i < NMONO; ++i)
            mono[i] = mono[PRED[i]] * ((VARI[i] == 0) ? q0 : ((VARI[i] == 1) ? q1 : q2));

        const float4* MS = (const float4*)&MhL[eh * 172];
        const float4* MA = (const float4*)&MhL[eh * 172 + 56];
        const float4* MB = (const float4*)&MhL[eh * 172 + 112];
        float aS = 0.f, aA = 0.f, aB = 0.f;
#pragma unroll
        for (int g = 0; g < 14; ++g) {
            float4 ms = MS[g], ma = MA[g], mb = MB[g];
            float p0 = mono[g * 4 + 0], p1 = mono[g * 4 + 1];
            float p2 = mono[g * 4 + 2], p3 = mono[g * 4 + 3];
            aS = fmaf(p0, ms.x, aS); aS = fmaf(p1, ms.y, aS);
            aS = fmaf(p2, ms.z, aS); aS = fmaf(p3, ms.w, aS);
            aA = fmaf(p0, ma.x, aA); aA = fmaf(p1, ma.y, aA);
            aA = fmaf(p2, ma.z, aA); aA = fmaf(p3, ma.w, aA);
            aB = fmaf(p0, mb.x, aB); aB = fmaf(p1, mb.y, aB);
            aB = fmaf(p2, mb.z, aB); aB = fmaf(p3, mb.w, aB);
        }
        float inv = 1.0f / aS;
        attL[sl][2 * eh]     = aA * inv;
        attL[sl][2 * eh + 1] = aB * inv;
    }
    __syncthreads();

    // ---- phase C: projection (32,16) @ W^T + bias -> (32,64) ----
    if (tid < 256) {
        const int e = tid & 63, r0 = tid >> 6;        // r0 0..3
#pragma unroll
        for (int j = 0; j < 8; ++j) {
            const int row = r0 + 4 * j;               // covers 0..31
            float acc2 = biasL[e];
#pragma unroll
            for (int jj = 0; jj < 16; ++jj)
                acc2 = fmaf(attL[row][jj], WtL[jj * 65 + e], acc2);
            out[((size_t)(b * NS + s0 + row)) * 64 + e] = acc2;
        }
    }
}

extern "C" void kernel_launch(void* const* d_in, const int* in_sizes, int n_in,
                              void* d_out, int out_size, void* d_ws, size_t ws_size,
                              hipStream_t stream) {
    const float* x     = (const float*)d_in[0];
    const float* theta = (const float*)d_in[1];
    const float* W     = (const float*)d_in[2];
    const float* bias  = (const float*)d_in[3];
    float* out = (float*)d_out;

    // one node, no workspace: 256 blocks (= 8 b x 32 s-chunks), 1 block/CU
    fused_qattn_kernel<<<dim3(NB * 32), dim3(768), 0, stream>>>(x, theta, W, bias, out);
}